// Round 18
// baseline (4901.451 us; speedup 1.0000x reference)
//
#include <hip/hip_runtime.h>
#include <math.h>

// ---------------------------------------------------------------------------
// 4-layer LSTM, B=64 T=512 D=H=1024. Persistent cooperative kernel, wavefront
// schedule (layer l works on t = s - l). Round-18 = round-17 with the A-read
// redundancy removed under the NOW-ISOLATED confounders:
//   - Wave role {mat(2) x kq(4)}, all 4 gates/wave: bw[4][8]=128 regs,
//     acc[4][4]=64 (r13-proven: compiles at 128 VGPR, no spill). Each A
//     fragment feeds 4 MFMAs -> LDS A-reads halve (512->256 b128/CU/step,
//     ~-1.3us). Chunk layout + staging + counted-vmcnt pipeline are
//     BYTE-IDENTICAL to r17; wave (mat,kq) reads kh-section (kq>>1), column
//     half (kq&1)*64B of each 128B row, XOR ^((row&7)<<4): uniform 8
//     dword-accesses/bank = the b128 floor (conflict-free, m136).
//   - Reduction: 8 WRITE-ONLY planes (plane = wave id, 128KB LDS, ONE
//     lgkmcnt sync). No RMW pass -- r13/r14's 2.35e8-conflict pattern was
//     tied to the 4-plane RMW; r17's write-only planes measure 6.7e7 with
//     the identical gate-read loop. Gate threads sum 8 planes (64 scalar
//     reads/thread; banks 2-way = free).
//   - l0 prefetch-touch dropped (r15: null effect; its trash LDS is planes).
// Unchanged from r17 (verified): gload_lds staging (linear dest, inverse-
// swizzled source), 3-buffer distance-2 counted-vmcnt kc pipeline
// (vmcnt(4)/vmcnt(0)-tail + raw s_barrier + sched_barrier pins), time-major
// x16, coalesced gate mapping gb=tid>>3 (h-store 8x32B bursts), fast gates,
// 2-hop relaxed-poll barrier + one acquire fence, h16 parity double-buffer,
// c-state in registers.
// ---------------------------------------------------------------------------

#define BSZ 64
#define TSZ 512
#define DSZ 1024
#define HSZ 1024
#define LSZ 4
#define NBLK 256
#define NTHR 512
#define NSTEP (TSZ + LSZ - 1)   // 515
#define BUFB 32768               // bytes per LDS staging buffer

typedef _Float16 half8  __attribute__((ext_vector_type(8)));
typedef _Float16 half4  __attribute__((ext_vector_type(4)));
typedef _Float16 half2v __attribute__((ext_vector_type(2)));
typedef float    f32x4  __attribute__((ext_vector_type(4)));
typedef float    f32x8  __attribute__((ext_vector_type(8)));

// workspace layout (bytes)
constexpr size_t N_X  = (size_t)BSZ * TSZ * DSZ;       // halfs
constexpr size_t N_H  = (size_t)2 * LSZ * BSZ * HSZ;   // halfs (h double buffer)
constexpr size_t OFF_X     = 0;
constexpr size_t OFF_H     = OFF_X + N_X * 2;
constexpr size_t OFF_FLAGS = OFF_H + N_H * 2;          // 256 flags, 64B apart
constexpr size_t OFF_GEN   = OFF_FLAGS + (size_t)NBLK * 64;
constexpr size_t BAR_BYTES = (size_t)NBLK * 64 + 64;

// fast gates (r11-r17-verified: absmax unchanged at 4.88e-4)
__device__ inline float fsig(float x) {
  return __builtin_amdgcn_rcpf(1.0f + __expf(-x));
}
__device__ inline float ftanh(float x) {
  float e = __expf(fminf(2.0f * x, 80.0f));
  return 1.0f - 2.0f * __builtin_amdgcn_rcpf(e + 1.0f);
}

__device__ inline void gload16(const void* g, void* l) {
  __builtin_amdgcn_global_load_lds(
      (const __attribute__((address_space(1))) void*)g,
      (__attribute__((address_space(3))) void*)l, 16, 0, 0);
}

// 2-hop grid barrier (r5/r16/r17-verified, relaxed polls + one acquire fence).
__device__ inline void gbar(unsigned* flags, unsigned* gen, unsigned tgt) {
  __syncthreads();
  if (blockIdx.x == 0) {
    const int t = threadIdx.x;
    if (t >= 1 && t < NBLK) {
      while (__hip_atomic_load(&flags[t * 16], __ATOMIC_RELAXED,
                               __HIP_MEMORY_SCOPE_AGENT) < tgt)
        __builtin_amdgcn_s_sleep(2);
    }
    __syncthreads();
    if (t == 0) {
      __hip_atomic_store(gen, tgt, __ATOMIC_RELAXED, __HIP_MEMORY_SCOPE_AGENT);
      __builtin_amdgcn_fence(__ATOMIC_ACQUIRE, "agent");
    }
  } else {
    if (threadIdx.x == 0) {
      __hip_atomic_store(&flags[(size_t)blockIdx.x * 16], tgt, __ATOMIC_RELAXED,
                         __HIP_MEMORY_SCOPE_AGENT);
      while (__hip_atomic_load(gen, __ATOMIC_RELAXED,
                               __HIP_MEMORY_SCOPE_AGENT) < tgt)
        __builtin_amdgcn_s_sleep(2);
      __builtin_amdgcn_fence(__ATOMIC_ACQUIRE, "agent");
    }
  }
  __syncthreads();
}

__global__ __launch_bounds__(NTHR, 1) void lstm_persistent(
    const float* __restrict__ xin, const float* __restrict__ Wih,
    const float* __restrict__ Whh, const float* __restrict__ bih,
    const float* __restrict__ bhh, float* __restrict__ out,
    char* __restrict__ ws)
{
  _Float16* x16   = (_Float16*)(ws + OFF_X);   // TIME-MAJOR: [t][b][d]
  _Float16* h16   = (_Float16*)(ws + OFF_H);
  unsigned* flags = (unsigned*)(ws + OFF_FLAGS);
  unsigned* gen   = (unsigned*)(ws + OFF_GEN);

  const int tid  = threadIdx.x;
  const int gtid = blockIdx.x * NTHR + tid;
  const int lane = tid & 63;
  const int w    = tid >> 6;        // wave 0..7
  const int mat  = w >> 2;          // 0 = input-side, 1 = recurrent
  const int kq   = w & 3;           // K-quarter: kh = kq>>1, half q = kq&1
  const int ln15 = lane & 15;
  const int lq   = lane >> 4;

  const int l  = blockIdx.x >> 6;   // layer
  const int cc = blockIdx.x & 63;   // column chunk (16 H-cols)
  const int c0 = cc * 16;

  // ---- weight preload (fp32 -> fp16, one time) ----
  // B-frag (r3-r17-verified convention): lane holds W[row = gate g,
  // col c0+ln15] at k = (kq>>1)*512 + kc*64 + (kq&1)*32 + lq*8 + 0..7.
  // bw[4][8] = 128 regs.
  const float* Wsel = mat ? Whh : Wih;
  half8 bw[4][8];
#pragma unroll
  for (int g = 0; g < 4; ++g) {
    const float* wrow =
        Wsel + (size_t)(l * 4096 + g * 1024 + c0 + ln15) * 1024 +
        (kq >> 1) * 512 + (kq & 1) * 32 + lq * 8;
#pragma unroll
    for (int kc = 0; kc < 8; ++kc) {
      f32x8 f = *(const f32x8*)(wrow + kc * 64);
      bw[g][kc] = __builtin_convertvector(f, half8);
    }
  }

  // ---- gate-math ownership (coalesced, r12-verified): row gb, cols gc/gc+1
  const int gb = tid >> 3;          // batch row 0..63
  const int gc = (tid & 7) * 2;     // even col 0..14
  float bsg[4][2];
#pragma unroll
  for (int g = 0; g < 4; ++g) {
    const int bb = l * 4096 + g * 1024 + c0 + gc;
    bsg[g][0] = bih[bb] + bhh[bb];
    bsg[g][1] = bih[bb + 1] + bhh[bb + 1];
  }
  float cr0 = 0.f, cr1 = 0.f;       // block-private c-state (registers)

  // ---- staging decomposition (step-invariant, r12/r17-verified) ----
  const int sb   = tid >> 3;                        // my staging batch row
  const int pswl = ((tid & 7) ^ (sb & 7)) << 4;     // swizzled source slot*16
  const int dstb = (tid >> 6) << 10;                // wave LDS base (w*1024)

  // ---- pre-phase: cast x to TIME-MAJOR fp16, zero h ----
  {
    const f32x4* s4 = (const f32x4*)xin;
    unsigned long long* xu = (unsigned long long*)x16;
    const int dq = DSZ / 4;                         // 256 (pow2)
    for (int i = gtid; i < (int)(N_X / 4); i += NBLK * NTHR) {
      const int d4  = i & (dq - 1);
      const int rem = i >> 8;                       // i / dq
      const int tt  = rem & (TSZ - 1);
      const int bb  = rem >> 9;                     // rem / TSZ
      half4 v = __builtin_convertvector(s4[i], half4);
      const size_t o = ((size_t)tt * BSZ + bb) * dq + d4;
      __hip_atomic_store(&xu[o], __builtin_bit_cast(unsigned long long, v),
                         __ATOMIC_RELAXED, __HIP_MEMORY_SCOPE_AGENT);
    }
    unsigned long long* hz = (unsigned long long*)h16;
    for (int i = gtid; i < (int)(N_H / 4); i += NBLK * NTHR)
      __hip_atomic_store(&hz[i], 0ull, __ATOMIC_RELAXED,
                         __HIP_MEMORY_SCOPE_AGENT);
  }
  unsigned btgt = 1;
  gbar(flags, gen, btgt++);

  // ---- LDS: 3 staging buffers (96KB) + 8 planes (128KB, overlaying) ----
  // plane p occupies floats [p*4096, (p+1)*4096) -> 8 planes = 128KB total.
  __shared__ __align__(16) char smem[4 * BUFB];
  float* pl = (float*)smem;

  const int lm1 = (l > 0) ? (l - 1) : 0;

  for (int s = 0; s < NSTEP; ++s) {
    const int t = s - l;
    if (t >= 0 && t < TSZ) {
      const int prevslot = (s + 1) & 1;
      const _Float16* hin  = h16 + (size_t)prevslot * (LSZ * BSZ * HSZ) +
                             (size_t)lm1 * (BSZ * HSZ);
      const _Float16* hown = h16 + (size_t)prevslot * (LSZ * BSZ * HSZ) +
                             (size_t)l * (BSZ * HSZ);
      const _Float16* base0 = (l == 0) ? x16 + (size_t)t * (BSZ * DSZ) : hin;

      const char* p0 = (const char*)(base0 + (size_t)sb * 1024) + pswl;
      const char* p1 = (const char*)(hown + (size_t)sb * HSZ) + pswl;

      auto stage = [&](int kc, int bsel) {
        const char* r0 = p0 + kc * 128;
        const char* r1 = p1 + kc * 128;
        char* d = smem + bsel * BUFB + dstb;
        gload16(r0,        d);           // (mat0, kh0)
        gload16(r0 + 1024, d + 8192);    // (mat0, kh1)
        gload16(r1,        d + 16384);   // (mat1, kh0)
        gload16(r1 + 1024, d + 24576);   // (mat1, kh1)
      };

      f32x4 acc[4][4] = {};   // [mt][g]

      // prologue: two stages in flight; ensure stage(0) landed
      stage(0, 0);
      stage(1, 1);
      __builtin_amdgcn_sched_barrier(0);
      asm volatile("s_waitcnt vmcnt(4)" ::: "memory");
      __builtin_amdgcn_s_barrier();
      __builtin_amdgcn_sched_barrier(0);

      const int rdoff = mat * 16384 + (kq >> 1) * 8192;  // chunk section
      const int rdo   = (kq & 1) * 64 + lq * 16;         // pre-XOR byte off
#pragma unroll
      for (int kc = 0; kc < 8; ++kc) {
        if (kc + 2 < 8) stage(kc + 2, (kc + 2) % 3);
        const char* rdb = smem + (kc % 3) * BUFB + rdoff;
        half8 a[4];
#pragma unroll
        for (int mt = 0; mt < 4; ++mt) {
          const int row = mt * 16 + ln15;
          a[mt] = *(const half8*)(rdb + row * 128 +
                                  (rdo ^ ((row & 7) << 4)));
        }
#pragma unroll
        for (int g = 0; g < 4; ++g)
#pragma unroll
          for (int mt = 0; mt < 4; ++mt)
            acc[mt][g] = __builtin_amdgcn_mfma_f32_16x16x32_f16(
                a[mt], bw[g][kc], acc[mt][g], 0, 0, 0);
        // counted wait: ensure stage(kc+1) landed; keep stage(kc+2) in flight
        __builtin_amdgcn_sched_barrier(0);
        if (kc <= 5)      asm volatile("s_waitcnt vmcnt(4)" ::: "memory");
        else if (kc == 6) asm volatile("s_waitcnt vmcnt(0)" ::: "memory");
        __builtin_amdgcn_s_barrier();
        __builtin_amdgcn_sched_barrier(0);
      }

      // ---- 8-plane reduction (write-only, one sync): plane = wave id ----
      // C/D map (r3-verified): C row = batch = mt*16+lq*4+r,
      // C col = gate-row v = g*16+ln15. bp = b ^ ((ln15&7)<<2) (r7-proven).
      {
        const int pbase = w * 4096;
#pragma unroll
        for (int mt = 0; mt < 4; ++mt)
#pragma unroll
          for (int g = 0; g < 4; ++g) {
            const int v  = g * 16 + ln15;
            const int bp = (mt * 16 + lq * 4) ^ ((ln15 & 7) << 2);
            *(f32x4*)&pl[pbase + v * 64 + bp] = acc[mt][g];
          }
      }
      __builtin_amdgcn_sched_barrier(0);
      asm volatile("s_waitcnt lgkmcnt(0)" ::: "memory");
      __builtin_amdgcn_s_barrier();
      __builtin_amdgcn_sched_barrier(0);

      // ---- gate math (fp32): thread owns (gb, cols gc/gc+1) ----
      {
        float z[4][2];
#pragma unroll
        for (int g = 0; g < 4; ++g)
#pragma unroll
          for (int j = 0; j < 2; ++j) {
            const int v  = g * 16 + gc + j;
            const int bp = gb ^ ((v & 7) << 2);
            float sum = 0.f;
#pragma unroll
            for (int p = 0; p < 8; ++p)
              sum += pl[p * 4096 + v * 64 + bp];
            z[g][j] = sum + bsg[g][j];
          }
        float cn0 = fsig(z[1][0]) * cr0 + fsig(z[0][0]) * ftanh(z[2][0]);
        float cn1 = fsig(z[1][1]) * cr1 + fsig(z[0][1]) * ftanh(z[2][1]);
        float hn0 = fsig(z[3][0]) * ftanh(cn0);
        float hn1 = fsig(z[3][1]) * ftanh(cn1);
        cr0 = cn0; cr1 = cn1;
        half2v hv; hv[0] = (_Float16)hn0; hv[1] = (_Float16)hn1;
        const size_t ho = (size_t)(s & 1) * (LSZ * BSZ * HSZ) +
                          (size_t)l * (BSZ * HSZ) + (size_t)gb * HSZ + c0 + gc;
        __hip_atomic_store((unsigned*)(h16 + ho),
                           __builtin_bit_cast(unsigned, hv),
                           __ATOMIC_RELAXED, __HIP_MEMORY_SCOPE_AGENT);
        if (l == LSZ - 1 && t == TSZ - 1) {
          out[(size_t)gb * HSZ + c0 + gc]     = hn0;
          out[(size_t)gb * HSZ + c0 + gc + 1] = hn1;
        }
      }
    }
    gbar(flags, gen, btgt++);
  }
}

extern "C" void kernel_launch(void* const* d_in, const int* in_sizes, int n_in,
                              void* d_out, int out_size, void* d_ws, size_t ws_size,
                              hipStream_t stream) {
  const float* x   = (const float*)d_in[0];
  const float* Wih = (const float*)d_in[1];
  const float* Whh = (const float*)d_in[2];
  const float* bih = (const float*)d_in[3];
  const float* bhh = (const float*)d_in[4];
  float* out = (float*)d_out;
  char*  ws  = (char*)d_ws;

  // barrier flags/gen zeroed every call (captured in graph -> re-zeroed
  // before the kernel on every replay)
  hipMemsetAsync(ws + OFF_FLAGS, 0, BAR_BYTES, stream);

  void* args[] = {(void*)&x, (void*)&Wih, (void*)&Whh, (void*)&bih,
                  (void*)&bhh, (void*)&out, (void*)&ws};
  hipLaunchCooperativeKernel((const void*)lstm_persistent, dim3(NBLK), dim3(NTHR),
                             args, 0, stream);
}

// Round 19
// 4743.385 us; speedup vs baseline: 1.0333x; 1.0333x over previous
//
#include <hip/hip_runtime.h>
#include <math.h>

// ---------------------------------------------------------------------------
// 4-layer LSTM, B=64 T=512 D=H=1024. Persistent cooperative kernel, wavefront
// schedule (layer l works on t = s - l). Round-19 = round-17 (best: 4.56ms)
// with HALVED sync granularity:
//   DIAGNOSIS: r18 closed the A-read-vs-reduction trade (every A-halving
//   role pays it back in reduction/gate LDS traffic; r17 is the balanced
//   optimum). r17 still pays ~12 block-barrier/waitcnt events per step
//   (8 kc + prologue + plane + gbar) at ~100-300cy skew each.
//   CHANGES:
//   1. Chunks of K=128: 4 per step (was 8). 2 x 64KB buffers, distance-1
//      prefetch; per-chunk compute ~1500cy >> ~500cy load latency, so the
//      end-of-chunk vmcnt(0) is fully covered (no counted-N needed).
//   2. Plane sync merged into the last chunk: kc=3 computes from buf1,
//      planes write to buf0 region (free since kc=2's barrier), ONE
//      lgkmcnt(0)+s_barrier before gate math. Block barriers/step ~12 -> ~7.
//   3. Staging: 8 gload16/thread/chunk. Same involution as r12/r17:
//      dest linear (region c*8192 + tid*16), source slot pre-swizzled
//      (sl&8)|((sl&7)^(b&7)); b&7 identical for the b and b+32 halves, so
//      one precomputed slot serves all 8 calls. Read XOR ^((row&7)<<4) on
//      256B rows = identity with the pre-swizzle; quad = slot^(row&7)
//      uniform over 8 quads = b128 bank floor (r12/r17-proven algebra).
// Unchanged from r17 (verified): wave role {mat x gatepair x Khalf},
// bw[2][16]=128 regs, acc[4][2]; 4 write-only planes + single lgkm sync;
// gate mapping gb=tid>>3 (8x32B h-store bursts); fast gates; time-major
// x16; 2-hop relaxed-poll barrier + one acquire fence; h16 parity double
// buffer; c-state in registers.
// ---------------------------------------------------------------------------

#define BSZ 64
#define TSZ 512
#define DSZ 1024
#define HSZ 1024
#define LSZ 4
#define NBLK 256
#define NTHR 512
#define NSTEP (TSZ + LSZ - 1)   // 515
#define BUFB 65536               // bytes per LDS staging buffer (K=128 chunk)

typedef _Float16 half8  __attribute__((ext_vector_type(8)));
typedef _Float16 half4  __attribute__((ext_vector_type(4)));
typedef _Float16 half2v __attribute__((ext_vector_type(2)));
typedef float    f32x4  __attribute__((ext_vector_type(4)));
typedef float    f32x8  __attribute__((ext_vector_type(8)));

// workspace layout (bytes)
constexpr size_t N_X  = (size_t)BSZ * TSZ * DSZ;       // halfs
constexpr size_t N_H  = (size_t)2 * LSZ * BSZ * HSZ;   // halfs (h double buffer)
constexpr size_t OFF_X     = 0;
constexpr size_t OFF_H     = OFF_X + N_X * 2;
constexpr size_t OFF_FLAGS = OFF_H + N_H * 2;          // 256 flags, 64B apart
constexpr size_t OFF_GEN   = OFF_FLAGS + (size_t)NBLK * 64;
constexpr size_t BAR_BYTES = (size_t)NBLK * 64 + 64;

// fast gates (r11-r18-verified: absmax unchanged at 4.88e-4)
__device__ inline float fsig(float x) {
  return __builtin_amdgcn_rcpf(1.0f + __expf(-x));
}
__device__ inline float ftanh(float x) {
  float e = __expf(fminf(2.0f * x, 80.0f));
  return 1.0f - 2.0f * __builtin_amdgcn_rcpf(e + 1.0f);
}

__device__ inline void gload16(const void* g, void* l) {
  __builtin_amdgcn_global_load_lds(
      (const __attribute__((address_space(1))) void*)g,
      (__attribute__((address_space(3))) void*)l, 16, 0, 0);
}

// 2-hop grid barrier (r5/r16/r17-verified, relaxed polls + one acquire fence).
__device__ inline void gbar(unsigned* flags, unsigned* gen, unsigned tgt) {
  __syncthreads();
  if (blockIdx.x == 0) {
    const int t = threadIdx.x;
    if (t >= 1 && t < NBLK) {
      while (__hip_atomic_load(&flags[t * 16], __ATOMIC_RELAXED,
                               __HIP_MEMORY_SCOPE_AGENT) < tgt)
        __builtin_amdgcn_s_sleep(2);
    }
    __syncthreads();
    if (t == 0) {
      __hip_atomic_store(gen, tgt, __ATOMIC_RELAXED, __HIP_MEMORY_SCOPE_AGENT);
      __builtin_amdgcn_fence(__ATOMIC_ACQUIRE, "agent");
    }
  } else {
    if (threadIdx.x == 0) {
      __hip_atomic_store(&flags[(size_t)blockIdx.x * 16], tgt, __ATOMIC_RELAXED,
                         __HIP_MEMORY_SCOPE_AGENT);
      while (__hip_atomic_load(gen, __ATOMIC_RELAXED,
                               __HIP_MEMORY_SCOPE_AGENT) < tgt)
        __builtin_amdgcn_s_sleep(2);
      __builtin_amdgcn_fence(__ATOMIC_ACQUIRE, "agent");
    }
  }
  __syncthreads();
}

__global__ __launch_bounds__(NTHR, 1) void lstm_persistent(
    const float* __restrict__ xin, const float* __restrict__ Wih,
    const float* __restrict__ Whh, const float* __restrict__ bih,
    const float* __restrict__ bhh, float* __restrict__ out,
    char* __restrict__ ws)
{
  _Float16* x16   = (_Float16*)(ws + OFF_X);   // TIME-MAJOR: [t][b][d]
  _Float16* h16   = (_Float16*)(ws + OFF_H);
  unsigned* flags = (unsigned*)(ws + OFF_FLAGS);
  unsigned* gen   = (unsigned*)(ws + OFF_GEN);

  const int tid  = threadIdx.x;
  const int gtid = blockIdx.x * NTHR + tid;
  const int lane = tid & 63;
  const int w    = tid >> 6;        // wave 0..7
  const int mat  = w >> 2;          // 0 = input-side, 1 = recurrent
  const int rp   = (w >> 1) & 1;    // gate pair (gates 2rp, 2rp+1)
  const int kh   = w & 1;           // K-half (512 k's)
  const int ln15 = lane & 15;
  const int lq   = lane >> 4;

  const int l  = blockIdx.x >> 6;   // layer
  const int cc = blockIdx.x & 63;   // column chunk (16 H-cols)
  const int c0 = cc * 16;

  // ---- weight preload into registers (fp32 -> fp16, one time) ----
  // B-frag (r3-r18-verified): lane holds W[row = gate 2rp+gl, col c0+ln15]
  // at k = kh*512 + ks*32 + lq*8 + 0..7. bw[gl][ks] = 128 regs.
  const float* Wsel = mat ? Whh : Wih;
  half8 bw[2][16];
#pragma unroll
  for (int gl = 0; gl < 2; ++gl) {
    const float* wrow =
        Wsel + (size_t)(l * 4096 + (rp * 2 + gl) * 1024 + c0 + ln15) * 1024 +
        kh * 512;
#pragma unroll
    for (int ks = 0; ks < 16; ++ks) {
      f32x8 f = *(const f32x8*)(wrow + ks * 32 + lq * 8);
      bw[gl][ks] = __builtin_convertvector(f, half8);
    }
  }

  // ---- gate-math ownership (coalesced, r12-verified): row gb, cols gc/gc+1
  const int gb = tid >> 3;          // batch row 0..63
  const int gc = (tid & 7) * 2;     // even col 0..14
  float bsg[4][2];
#pragma unroll
  for (int g = 0; g < 4; ++g) {
    const int bb = l * 4096 + g * 1024 + c0 + gc;
    bsg[g][0] = bih[bb] + bhh[bb];
    bsg[g][1] = bih[bb + 1] + bhh[bb + 1];
  }
  float cr0 = 0.f, cr1 = 0.f;       // block-private c-state (registers)

  // ---- staging decomposition (step-invariant) ----
  // Buffer = [mat(2)][kh(2)][b(64)][16 slots x 16B] = 64KB. 8 gload16/thread:
  // region c (8KB) = mat(c>>2), kh((c>>1)&1), b-half(c&1); within region,
  // dest = tid*16 -> lane covers b = bhalf*32 + w*4 + (lane>>4), sl=lane&15.
  // Source slot pre-swizzled: (sl&8)|((sl&7)^(b&7)); (b+32)&7 == b&7 so one
  // slot serves both halves.
  const int bA   = w * 4 + (lane >> 4);             // staging row (low half)
  const int slg  = (((ln15 & 8) | ((ln15 & 7) ^ (bA & 7)))) << 4;
  const int dstb = tid * 16;

  // ---- pre-phase: cast x to TIME-MAJOR fp16, zero h ----
  {
    const f32x4* s4 = (const f32x4*)xin;
    unsigned long long* xu = (unsigned long long*)x16;
    const int dq = DSZ / 4;                         // 256 (pow2)
    for (int i = gtid; i < (int)(N_X / 4); i += NBLK * NTHR) {
      const int d4  = i & (dq - 1);
      const int rem = i >> 8;                       // i / dq
      const int tt  = rem & (TSZ - 1);
      const int bb  = rem >> 9;                     // rem / TSZ
      half4 v = __builtin_convertvector(s4[i], half4);
      const size_t o = ((size_t)tt * BSZ + bb) * dq + d4;
      __hip_atomic_store(&xu[o], __builtin_bit_cast(unsigned long long, v),
                         __ATOMIC_RELAXED, __HIP_MEMORY_SCOPE_AGENT);
    }
    unsigned long long* hz = (unsigned long long*)h16;
    for (int i = gtid; i < (int)(N_H / 4); i += NBLK * NTHR)
      __hip_atomic_store(&hz[i], 0ull, __ATOMIC_RELAXED,
                         __HIP_MEMORY_SCOPE_AGENT);
  }
  unsigned btgt = 1;
  gbar(flags, gen, btgt++);

  // ---- LDS: 2 staging buffers (64KB each); 4 planes overlay buf0 ----
  __shared__ __align__(16) char smem[2 * BUFB];
  float* pl = (float*)smem;        // f32[4][64][64] after final kc barrier

  const int lm1 = (l > 0) ? (l - 1) : 0;

  for (int s = 0; s < NSTEP; ++s) {
    const int t = s - l;
    if (t >= 0 && t < TSZ) {
      const int prevslot = (s + 1) & 1;
      const _Float16* hin  = h16 + (size_t)prevslot * (LSZ * BSZ * HSZ) +
                             (size_t)lm1 * (BSZ * HSZ);
      const _Float16* hown = h16 + (size_t)prevslot * (LSZ * BSZ * HSZ) +
                             (size_t)l * (BSZ * HSZ);
      const _Float16* base0 = (l == 0) ? x16 + (size_t)t * (BSZ * DSZ) : hin;

      // my 4 pre-swizzled source row pointers (mat0/mat1 x bA/bA+32)
      const char* q0A = (const char*)(base0 + (size_t)bA * 1024) + slg;
      const char* q0B = q0A + 32 * 2048;
      const char* q1A = (const char*)(hown + (size_t)bA * 1024) + slg;
      const char* q1B = q1A + 32 * 2048;

      // stage one K=128 chunk (both K-halves, both mats): 8 x 8KB regions
      auto stage = [&](int kc, int bsel) {
        const int kb = kc * 256;
        char* d = smem + bsel * BUFB + dstb;
        gload16(q0A + kb,        d);             // mat0, kh0, b 0..31
        gload16(q0B + kb,        d + 8192);      // mat0, kh0, b 32..63
        gload16(q0A + 1024 + kb, d + 16384);     // mat0, kh1, b 0..31
        gload16(q0B + 1024 + kb, d + 24576);     // mat0, kh1, b 32..63
        gload16(q1A + kb,        d + 32768);     // mat1, kh0, b 0..31
        gload16(q1B + kb,        d + 40960);     // mat1, kh0, b 32..63
        gload16(q1A + 1024 + kb, d + 49152);     // mat1, kh1, b 0..31
        gload16(q1B + 1024 + kb, d + 57344);     // mat1, kh1, b 32..63
      };

      f32x4 acc[4][2] = {};   // [mt][gl]

      stage(0, 0);
      __builtin_amdgcn_sched_barrier(0);
      asm volatile("s_waitcnt vmcnt(0)" ::: "memory");
      __builtin_amdgcn_s_barrier();
      __builtin_amdgcn_sched_barrier(0);

      const int rdoff = mat * 32768 + kh * 16384;
#pragma unroll
      for (int kc = 0; kc < 4; ++kc) {
        if (kc < 3) stage(kc + 1, (kc + 1) & 1);
        const char* rdb = smem + (kc & 1) * BUFB + rdoff;
#pragma unroll
        for (int ksl = 0; ksl < 4; ++ksl) {
#pragma unroll
          for (int mt = 0; mt < 4; ++mt) {
            const int row = mt * 16 + ln15;
            const half8 a = *(const half8*)(rdb + row * 256 +
                                            ((ksl * 64 + lq * 16) ^
                                             ((row & 7) << 4)));
            acc[mt][0] = __builtin_amdgcn_mfma_f32_16x16x32_f16(
                a, bw[0][kc * 4 + ksl], acc[mt][0], 0, 0, 0);
            acc[mt][1] = __builtin_amdgcn_mfma_f32_16x16x32_f16(
                a, bw[1][kc * 4 + ksl], acc[mt][1], 0, 0, 0);
          }
        }
        if (kc < 3) {
          // stage(kc+1) had a full compute phase (~1500cy) to land
          __builtin_amdgcn_sched_barrier(0);
          asm volatile("s_waitcnt vmcnt(0)" ::: "memory");
          __builtin_amdgcn_s_barrier();
          __builtin_amdgcn_sched_barrier(0);
        }
      }

      // ---- 4-plane write (into buf0 region; free since kc=2's barrier) ----
      // C/D map (r3-verified): C row = batch = mt*16+lq*4+r,
      // C col = gate-row v = (2rp+gl)*16+ln15. bp = b ^ ((ln15&7)<<2).
      {
        const int pbase = (mat * 2 + kh) * 4096;
#pragma unroll
        for (int mt = 0; mt < 4; ++mt)
#pragma unroll
          for (int gl = 0; gl < 2; ++gl) {
            const int v  = (rp * 2 + gl) * 16 + ln15;
            const int bp = (mt * 16 + lq * 4) ^ ((ln15 & 7) << 2);
            *(f32x4*)&pl[pbase + v * 64 + bp] = acc[mt][gl];
          }
      }
      __builtin_amdgcn_sched_barrier(0);
      asm volatile("s_waitcnt lgkmcnt(0)" ::: "memory");
      __builtin_amdgcn_s_barrier();
      __builtin_amdgcn_sched_barrier(0);

      // ---- gate math (fp32): thread owns (gb, cols gc/gc+1) ----
      {
        float z[4][2];
#pragma unroll
        for (int g = 0; g < 4; ++g)
#pragma unroll
          for (int j = 0; j < 2; ++j) {
            const int v  = g * 16 + gc + j;
            const int bp = gb ^ ((v & 7) << 2);
            z[g][j] = pl[0 * 4096 + v * 64 + bp] +
                      pl[1 * 4096 + v * 64 + bp] +
                      pl[2 * 4096 + v * 64 + bp] +
                      pl[3 * 4096 + v * 64 + bp] + bsg[g][j];
          }
        float cn0 = fsig(z[1][0]) * cr0 + fsig(z[0][0]) * ftanh(z[2][0]);
        float cn1 = fsig(z[1][1]) * cr1 + fsig(z[0][1]) * ftanh(z[2][1]);
        float hn0 = fsig(z[3][0]) * ftanh(cn0);
        float hn1 = fsig(z[3][1]) * ftanh(cn1);
        cr0 = cn0; cr1 = cn1;
        half2v hv; hv[0] = (_Float16)hn0; hv[1] = (_Float16)hn1;
        const size_t ho = (size_t)(s & 1) * (LSZ * BSZ * HSZ) +
                          (size_t)l * (BSZ * HSZ) + (size_t)gb * HSZ + c0 + gc;
        __hip_atomic_store((unsigned*)(h16 + ho),
                           __builtin_bit_cast(unsigned, hv),
                           __ATOMIC_RELAXED, __HIP_MEMORY_SCOPE_AGENT);
        if (l == LSZ - 1 && t == TSZ - 1) {
          out[(size_t)gb * HSZ + c0 + gc]     = hn0;
          out[(size_t)gb * HSZ + c0 + gc + 1] = hn1;
        }
      }
    }
    gbar(flags, gen, btgt++);
  }
}

extern "C" void kernel_launch(void* const* d_in, const int* in_sizes, int n_in,
                              void* d_out, int out_size, void* d_ws, size_t ws_size,
                              hipStream_t stream) {
  const float* x   = (const float*)d_in[0];
  const float* Wih = (const float*)d_in[1];
  const float* Whh = (const float*)d_in[2];
  const float* bih = (const float*)d_in[3];
  const float* bhh = (const float*)d_in[4];
  float* out = (float*)d_out;
  char*  ws  = (char*)d_ws;

  // barrier flags/gen zeroed every call (captured in graph -> re-zeroed
  // before the kernel on every replay)
  hipMemsetAsync(ws + OFF_FLAGS, 0, BAR_BYTES, stream);

  void* args[] = {(void*)&x, (void*)&Wih, (void*)&Whh, (void*)&bih,
                  (void*)&bhh, (void*)&out, (void*)&ws};
  hipLaunchCooperativeKernel((const void*)lstm_persistent, dim3(NBLK), dim3(NTHR),
                             args, 0, stream);
}

// Round 20
// 4220.996 us; speedup vs baseline: 1.1612x; 1.1238x over previous
//
#include <hip/hip_runtime.h>
#include <math.h>

// ---------------------------------------------------------------------------
// 4-layer LSTM, B=64 T=512 D=H=1024. Persistent cooperative kernel, wavefront
// schedule (layer l works on t = s - l). Round-20 = round-17 (best: 4.56ms)
// with the grid barrier replaced by DATAFLOW SYNC:
//   DIAGNOSIS: r16 (topology) and r19 (granularity) nulls leave the grid
//   barrier's SEMANTICS as the untested cost: every step pays the max of
//   256 block finish times. True deps are local: layer l step s needs
//   {layer l, layer l-1} completed s-1 and layer l+1 completed s-2
//   (anti-clobber).
//   CHANGES:
//   1. Per-block progress flags (completed-step counts). Before step s a
//      layer-l block polls: own 64 flags >= s, layer-(l-1) >= s,
//      layer-(l+1) >= s-1 (one flag/thread, relaxed agent loads, one
//      acquire fence after). Stragglers stall only neighbor layer groups
//      for one step; jitter telescopes instead of accumulating.
//   2. h16 deepened to 3 slots (slot = s mod 3): legalizes the 1-step
//      producer lead the relaxed anti-dep allows (write s%3 clobbers h from
//      s-3, read at s-2 -> need above-layer count >= s-1 only).
//   3. Pre-phase keeps ONE full 2-hop barrier (x16/h-zero visibility).
// Unchanged from r17 (verified): 3-buffer distance-2 counted-vmcnt kc
// pipeline, 4 write-only planes + single lgkm sync, wave role
// {mat x gatepair x Khalf} bw[2][16], gload_lds staging (linear dest,
// inverse-swizzled source), time-major x16 + l0 prefetch-touch, coalesced
// gate mapping gb=tid>>3, fast gates, c-state in registers.
// ---------------------------------------------------------------------------

#define BSZ 64
#define TSZ 512
#define DSZ 1024
#define HSZ 1024
#define LSZ 4
#define NBLK 256
#define NTHR 512
#define NSTEP (TSZ + LSZ - 1)   // 515
#define BUFB 32768               // bytes per LDS staging buffer

typedef _Float16 half8  __attribute__((ext_vector_type(8)));
typedef _Float16 half4  __attribute__((ext_vector_type(4)));
typedef _Float16 half2v __attribute__((ext_vector_type(2)));
typedef float    f32x4  __attribute__((ext_vector_type(4)));
typedef float    f32x8  __attribute__((ext_vector_type(8)));

// workspace layout (bytes)
constexpr size_t N_X  = (size_t)BSZ * TSZ * DSZ;       // halfs
constexpr size_t N_H  = (size_t)3 * LSZ * BSZ * HSZ;   // halfs (3-slot h)
constexpr size_t HSLOT = (size_t)LSZ * BSZ * HSZ;      // halfs per slot
constexpr size_t OFF_X     = 0;
constexpr size_t OFF_H     = OFF_X + N_X * 2;
constexpr size_t OFF_FLAGS = OFF_H + N_H * 2;          // pre-phase barrier
constexpr size_t OFF_GEN   = OFF_FLAGS + (size_t)NBLK * 64;
constexpr size_t OFF_DF    = OFF_GEN + 64;             // dataflow flags
constexpr size_t BAR_BYTES = (size_t)NBLK * 64 + 64 + (size_t)NBLK * 64;

// fast gates (r11-r19-verified: absmax unchanged at 4.88e-4)
__device__ inline float fsig(float x) {
  return __builtin_amdgcn_rcpf(1.0f + __expf(-x));
}
__device__ inline float ftanh(float x) {
  float e = __expf(fminf(2.0f * x, 80.0f));
  return 1.0f - 2.0f * __builtin_amdgcn_rcpf(e + 1.0f);
}

__device__ inline void gload16(const void* g, void* l) {
  __builtin_amdgcn_global_load_lds(
      (const __attribute__((address_space(1))) void*)g,
      (__attribute__((address_space(3))) void*)l, 16, 0, 0);
}

// 2-hop full grid barrier (r5/r16/r17-verified) -- pre-phase only.
__device__ inline void gbar(unsigned* flags, unsigned* gen, unsigned tgt) {
  __syncthreads();
  if (blockIdx.x == 0) {
    const int t = threadIdx.x;
    if (t >= 1 && t < NBLK) {
      while (__hip_atomic_load(&flags[t * 16], __ATOMIC_RELAXED,
                               __HIP_MEMORY_SCOPE_AGENT) < tgt)
        __builtin_amdgcn_s_sleep(2);
    }
    __syncthreads();
    if (t == 0) {
      __hip_atomic_store(gen, tgt, __ATOMIC_RELAXED, __HIP_MEMORY_SCOPE_AGENT);
      __builtin_amdgcn_fence(__ATOMIC_ACQUIRE, "agent");
    }
  } else {
    if (threadIdx.x == 0) {
      __hip_atomic_store(&flags[(size_t)blockIdx.x * 16], tgt, __ATOMIC_RELAXED,
                         __HIP_MEMORY_SCOPE_AGENT);
      while (__hip_atomic_load(gen, __ATOMIC_RELAXED,
                               __HIP_MEMORY_SCOPE_AGENT) < tgt)
        __builtin_amdgcn_s_sleep(2);
      __builtin_amdgcn_fence(__ATOMIC_ACQUIRE, "agent");
    }
  }
  __syncthreads();
}

// dataflow wait: before step s, layer l needs own & below counts >= s,
// above count >= s-1. One flag per thread; relaxed polls; one acquire fence.
__device__ inline void dwait(unsigned* df, int l, unsigned s) {
  const int t = threadIdx.x;
  if (t < 64) {
    while (__hip_atomic_load(&df[(size_t)(l * 64 + t) * 16], __ATOMIC_RELAXED,
                             __HIP_MEMORY_SCOPE_AGENT) < s)
      __builtin_amdgcn_s_sleep(2);
  } else if (t < 128) {
    if (l > 0) {
      while (__hip_atomic_load(&df[(size_t)((l - 1) * 64 + (t - 64)) * 16],
                               __ATOMIC_RELAXED,
                               __HIP_MEMORY_SCOPE_AGENT) < s)
        __builtin_amdgcn_s_sleep(2);
    }
  } else if (t < 192) {
    if (l < LSZ - 1 && s > 0) {
      while (__hip_atomic_load(&df[(size_t)((l + 1) * 64 + (t - 128)) * 16],
                               __ATOMIC_RELAXED,
                               __HIP_MEMORY_SCOPE_AGENT) < s - 1)
        __builtin_amdgcn_s_sleep(2);
    }
  }
  __syncthreads();
  if (t == 0) __builtin_amdgcn_fence(__ATOMIC_ACQUIRE, "agent");
  __syncthreads();
}

// dataflow post: entry syncthreads drains this block's stores (vmcnt(0)
// before s_barrier), then tid0 publishes the completed-step count.
__device__ inline void dpost(unsigned* df, unsigned cnt) {
  __syncthreads();
  if (threadIdx.x == 0)
    __hip_atomic_store(&df[(size_t)blockIdx.x * 16], cnt, __ATOMIC_RELAXED,
                       __HIP_MEMORY_SCOPE_AGENT);
}

__global__ __launch_bounds__(NTHR, 1) void lstm_persistent(
    const float* __restrict__ xin, const float* __restrict__ Wih,
    const float* __restrict__ Whh, const float* __restrict__ bih,
    const float* __restrict__ bhh, float* __restrict__ out,
    char* __restrict__ ws)
{
  _Float16* x16   = (_Float16*)(ws + OFF_X);   // TIME-MAJOR: [t][b][d]
  _Float16* h16   = (_Float16*)(ws + OFF_H);   // 3 slots
  unsigned* flags = (unsigned*)(ws + OFF_FLAGS);
  unsigned* gen   = (unsigned*)(ws + OFF_GEN);
  unsigned* df    = (unsigned*)(ws + OFF_DF);

  const int tid  = threadIdx.x;
  const int gtid = blockIdx.x * NTHR + tid;
  const int lane = tid & 63;
  const int w    = tid >> 6;        // wave 0..7
  const int mat  = w >> 2;          // 0 = input-side, 1 = recurrent
  const int rp   = (w >> 1) & 1;    // gate pair (gates 2rp, 2rp+1)
  const int kh   = w & 1;           // K-half (512 k's)
  const int ln15 = lane & 15;
  const int lq   = lane >> 4;

  const int l  = blockIdx.x >> 6;   // layer
  const int cc = blockIdx.x & 63;   // column chunk (16 H-cols)
  const int c0 = cc * 16;

  // ---- weight preload into registers (fp32 -> fp16, one time) ----
  const float* Wsel = mat ? Whh : Wih;
  half8 bw[2][16];
#pragma unroll
  for (int gl = 0; gl < 2; ++gl) {
    const float* wrow =
        Wsel + (size_t)(l * 4096 + (rp * 2 + gl) * 1024 + c0 + ln15) * 1024 +
        kh * 512;
#pragma unroll
    for (int ks = 0; ks < 16; ++ks) {
      f32x8 f = *(const f32x8*)(wrow + ks * 32 + lq * 8);
      bw[gl][ks] = __builtin_convertvector(f, half8);
    }
  }

  // ---- gate-math ownership (coalesced, r12-verified): row gb, cols gc/gc+1
  const int gb = tid >> 3;          // batch row 0..63
  const int gc = (tid & 7) * 2;     // even col 0..14
  float bsg[4][2];
#pragma unroll
  for (int g = 0; g < 4; ++g) {
    const int bb = l * 4096 + g * 1024 + c0 + gc;
    bsg[g][0] = bih[bb] + bhh[bb];
    bsg[g][1] = bih[bb + 1] + bhh[bb + 1];
  }
  float cr0 = 0.f, cr1 = 0.f;       // block-private c-state (registers)

  // ---- staging decomposition (step-invariant, r12/r17-verified) ----
  const int sb   = tid >> 3;                        // my staging batch row
  const int pswl = ((tid & 7) ^ (sb & 7)) << 4;     // swizzled source slot*16
  const int dstb = (tid >> 6) << 10;                // wave LDS base (w*1024)

  // ---- pre-phase: cast x to TIME-MAJOR fp16, zero h (3 slots) ----
  {
    const f32x4* s4 = (const f32x4*)xin;
    unsigned long long* xu = (unsigned long long*)x16;
    const int dq = DSZ / 4;                         // 256 (pow2)
    for (int i = gtid; i < (int)(N_X / 4); i += NBLK * NTHR) {
      const int d4  = i & (dq - 1);
      const int rem = i >> 8;                       // i / dq
      const int tt  = rem & (TSZ - 1);
      const int bb  = rem >> 9;                     // rem / TSZ
      half4 v = __builtin_convertvector(s4[i], half4);
      const size_t o = ((size_t)tt * BSZ + bb) * dq + d4;
      __hip_atomic_store(&xu[o], __builtin_bit_cast(unsigned long long, v),
                         __ATOMIC_RELAXED, __HIP_MEMORY_SCOPE_AGENT);
    }
    unsigned long long* hz = (unsigned long long*)h16;
    for (int i = gtid; i < (int)(N_H / 4); i += NBLK * NTHR)
      __hip_atomic_store(&hz[i], 0ull, __ATOMIC_RELAXED,
                         __HIP_MEMORY_SCOPE_AGENT);
  }
  gbar(flags, gen, 1u);   // one full barrier: x16/h zeros visible everywhere

  // ---- LDS: 3 staging buffers (96KB); 4 planes overlay buf0+buf1 ----
  __shared__ __align__(16) char smem[3 * BUFB];
  float* pl = (float*)smem;        // f32[4][64][64] after final kc barrier

  const int lm1 = (l > 0) ? (l - 1) : 0;
  int wslot = 0;                    // s % 3

  for (int s = 0; s < NSTEP; ++s) {
    dwait(df, l, (unsigned)s);

    const int t = s - l;
    if (t >= 0 && t < TSZ) {
      const int rslot = (wslot + 2) % 3;   // (s-1) mod 3
      const _Float16* hin  = h16 + (size_t)rslot * HSLOT +
                             (size_t)lm1 * (BSZ * HSZ);
      const _Float16* hown = h16 + (size_t)rslot * HSLOT +
                             (size_t)l * (BSZ * HSZ);
      const _Float16* base0 = (l == 0) ? x16 + (size_t)t * (BSZ * DSZ) : hin;

      const char* p0 = (const char*)(base0 + (size_t)sb * 1024) + pswl;
      const char* p1 = (const char*)(hown + (size_t)sb * HSZ) + pswl;

      auto stage = [&](int kc, int bsel) {
        const char* r0 = p0 + kc * 128;
        const char* r1 = p1 + kc * 128;
        char* d = smem + bsel * BUFB + dstb;
        gload16(r0,        d);           // (mat0, kh0)
        gload16(r0 + 1024, d + 8192);    // (mat0, kh1)
        gload16(r1,        d + 16384);   // (mat1, kh0)
        gload16(r1 + 1024, d + 24576);   // (mat1, kh1)
      };

      f32x4 acc[4][2] = {};   // [mt][gl]

      // prologue: two stages in flight; ensure stage(0) landed
      stage(0, 0);
      stage(1, 1);
      __builtin_amdgcn_sched_barrier(0);
      asm volatile("s_waitcnt vmcnt(4)" ::: "memory");
      __builtin_amdgcn_s_barrier();
      __builtin_amdgcn_sched_barrier(0);

      const int rdoff = mat * 16384 + kh * 8192;
#pragma unroll
      for (int kc = 0; kc < 8; ++kc) {
        if (kc + 2 < 8) stage(kc + 2, (kc + 2) % 3);
        const char* rdb = smem + (kc % 3) * BUFB + rdoff;
#pragma unroll
        for (int ksl = 0; ksl < 2; ++ksl) {
#pragma unroll
          for (int mt = 0; mt < 4; ++mt) {
            const int row = mt * 16 + ln15;
            const half8 a = *(const half8*)(rdb + row * 128 +
                                            ((ksl * 64 + lq * 16) ^
                                             ((row & 7) << 4)));
            acc[mt][0] = __builtin_amdgcn_mfma_f32_16x16x32_f16(
                a, bw[0][kc * 2 + ksl], acc[mt][0], 0, 0, 0);
            acc[mt][1] = __builtin_amdgcn_mfma_f32_16x16x32_f16(
                a, bw[1][kc * 2 + ksl], acc[mt][1], 0, 0, 0);
          }
        }
        // counted wait: ensure stage(kc+1) landed; keep stage(kc+2) in flight
        __builtin_amdgcn_sched_barrier(0);
        if (kc <= 5)      asm volatile("s_waitcnt vmcnt(4)" ::: "memory");
        else if (kc == 6) asm volatile("s_waitcnt vmcnt(0)" ::: "memory");
        __builtin_amdgcn_s_barrier();
        __builtin_amdgcn_sched_barrier(0);
      }

      // ---- layer-0 prefetch-touch of NEXT x-slice into L2 (buf2 trash) ----
      // Drained by dpost's __syncthreads (overlapped with the sync wait).
      if (l == 0 && t + 1 < TSZ) {
        const char* xnext =
            (const char*)(x16 + (size_t)(t + 1) * (BSZ * DSZ)) +
            ((cc >> 3) & 7) * 16384;
        char* trash = smem + 2 * BUFB + dstb;
        gload16(xnext + tid * 16, trash);
        gload16(xnext + 8192 + tid * 16, trash);
      }

      // ---- 4-plane reduction (one sync): plane p = mat*2+kh ----
      {
        const int pbase = (mat * 2 + kh) * 4096;
#pragma unroll
        for (int mt = 0; mt < 4; ++mt)
#pragma unroll
          for (int gl = 0; gl < 2; ++gl) {
            const int v  = (rp * 2 + gl) * 16 + ln15;
            const int bp = (mt * 16 + lq * 4) ^ ((ln15 & 7) << 2);
            *(f32x4*)&pl[pbase + v * 64 + bp] = acc[mt][gl];
          }
      }
      __builtin_amdgcn_sched_barrier(0);
      asm volatile("s_waitcnt lgkmcnt(0)" ::: "memory");
      __builtin_amdgcn_s_barrier();
      __builtin_amdgcn_sched_barrier(0);

      // ---- gate math (fp32): thread owns (gb, cols gc/gc+1) ----
      {
        float z[4][2];
#pragma unroll
        for (int g = 0; g < 4; ++g)
#pragma unroll
          for (int j = 0; j < 2; ++j) {
            const int v  = g * 16 + gc + j;
            const int bp = gb ^ ((v & 7) << 2);
            z[g][j] = pl[0 * 4096 + v * 64 + bp] +
                      pl[1 * 4096 + v * 64 + bp] +
                      pl[2 * 4096 + v * 64 + bp] +
                      pl[3 * 4096 + v * 64 + bp] + bsg[g][j];
          }
        float cn0 = fsig(z[1][0]) * cr0 + fsig(z[0][0]) * ftanh(z[2][0]);
        float cn1 = fsig(z[1][1]) * cr1 + fsig(z[0][1]) * ftanh(z[2][1]);
        float hn0 = fsig(z[3][0]) * ftanh(cn0);
        float hn1 = fsig(z[3][1]) * ftanh(cn1);
        cr0 = cn0; cr1 = cn1;
        half2v hv; hv[0] = (_Float16)hn0; hv[1] = (_Float16)hn1;
        const size_t ho = (size_t)wslot * HSLOT + (size_t)l * (BSZ * HSZ) +
                          (size_t)gb * HSZ + c0 + gc;
        __hip_atomic_store((unsigned*)(h16 + ho),
                           __builtin_bit_cast(unsigned, hv),
                           __ATOMIC_RELAXED, __HIP_MEMORY_SCOPE_AGENT);
        if (l == LSZ - 1 && t == TSZ - 1) {
          out[(size_t)gb * HSZ + c0 + gc]     = hn0;
          out[(size_t)gb * HSZ + c0 + gc + 1] = hn1;
        }
      }
    }

    dpost(df, (unsigned)(s + 1));
    wslot = (wslot == 2) ? 0 : wslot + 1;
  }
}

extern "C" void kernel_launch(void* const* d_in, const int* in_sizes, int n_in,
                              void* d_out, int out_size, void* d_ws, size_t ws_size,
                              hipStream_t stream) {
  const float* x   = (const float*)d_in[0];
  const float* Wih = (const float*)d_in[1];
  const float* Whh = (const float*)d_in[2];
  const float* bih = (const float*)d_in[3];
  const float* bhh = (const float*)d_in[4];
  float* out = (float*)d_out;
  char*  ws  = (char*)d_ws;

  // barrier + dataflow flags zeroed every call (captured in graph ->
  // re-zeroed before the kernel on every replay)
  hipMemsetAsync(ws + OFF_FLAGS, 0, BAR_BYTES, stream);

  void* args[] = {(void*)&x, (void*)&Wih, (void*)&Whh, (void*)&bih,
                  (void*)&bhh, (void*)&out, (void*)&ws};
  hipLaunchCooperativeKernel((const void*)lstm_persistent, dim3(NBLK), dim3(NTHR),
                             args, 0, stream);
}